// Round 24
// baseline (105.760 us; speedup 1.0000x reference)
//
#include <hip/hip_runtime.h>
#include <hip/hip_bf16.h>

typedef short  short8  __attribute__((ext_vector_type(8)));
typedef float  f32x16  __attribute__((ext_vector_type(16)));

#define XB 16
#define XC 128
#define XH 64
#define XW 64
#define XHW 4096
#define PSTR 72            // padded elems per pixel (64 data + 8 pad), 144 B
#define XPROW 76           // padded image width/height

__device__ __forceinline__ unsigned short f2bf(float f) {
    union { float f; unsigned int u; } v; v.f = f;
    unsigned int r = (v.u + 0x7fffu + ((v.u >> 16) & 1u)) >> 16;
    return (unsigned short)r;
}

__device__ __forceinline__ void gload16(const unsigned short* g, unsigned short* s) {
    __builtin_amdgcn_global_load_lds(
        (const __attribute__((address_space(1))) void*)g,
        (__attribute__((address_space(3))) void*)s, 16, 0, 0);
}

// ---------------- K1: fused pad+convert+rowmeans (blocks 0..1215) + filter pack (1216..1553) ----------------
__global__ void k_prep(const float* __restrict__ x, unsigned short* __restrict__ xpad,
                       float* __restrict__ rs,
                       const float* __restrict__ lk, unsigned short* __restrict__ fpack) {
    int blk = blockIdx.x;
    int t = threadIdx.x;
    if (blk >= 1216) {
        int tidx = (blk - 1216) * 256 + t;       // < 86,528 exactly
        int l   = tidx & 63;
        int g   = (tidx >> 6) & 1;
        int ks  = (tidx >> 7) & 3;
        int tap = tidx >> 9;
        int oc  = g * 32 + (l & 31);
        int ic0 = ks * 16 + (l >> 5) * 8;
        unsigned short tmp[8];
#pragma unroll
        for (int e = 0; e < 8; ++e)
            tmp[e] = f2bf(lk[(size_t)(oc * 64 + ic0 + e) * 169 + tap]);
        unsigned int u[4];
#pragma unroll
        for (int k = 0; k < 4; ++k) u[k] = (unsigned int)tmp[2 * k] | ((unsigned int)tmp[2 * k + 1] << 16);
        uint4 v = {u[0], u[1], u[2], u[3]};
        *(uint4*)(fpack + (size_t)tidx * 8) = v;
        return;
    }
    int b = blk / 76, hp = blk - b * 76;
    unsigned short* dst = xpad + (size_t)(b * XPROW + hp) * XPROW * PSTR;
    uint4 z = {0u, 0u, 0u, 0u};
    if (hp < 6 || hp >= 70) {           // full zero row: 76*72 elems = 684 uint4
        for (int k = t; k < 684; k += 256) ((uint4*)dst)[k] = z;
        return;
    }
    int h = hp - 6;
    __shared__ float tile[64][65];
    __shared__ float ps[4][64];
    {
        int w = t & 63, cg = t >> 6;
#pragma unroll
        for (int k = 0; k < 16; ++k) {
            int c = cg * 16 + k;
            tile[c][w] = x[(size_t)b * XC * XHW + (size_t)c * XHW + h * 64 + w];
        }
    }
    __syncthreads();
    {
        int c = t & 63, q = t >> 6;
        float s = 0.f;
#pragma unroll
        for (int k = 0; k < 16; ++k) s += tile[c][q * 16 + k];
        ps[q][c] = s;
    }
    __syncthreads();
    if (t < 64) {
        float tot = ps[0][t] + ps[1][t] + ps[2][t] + ps[3][t];
        rs[b * 4096 + h * 64 + t] = tot * (1.f / 4096.f);
    }
    if (t < 108) {
        int px = t / 9, u = t - (t / 9) * 9;
        int ppx = px < 6 ? px : px + 64;
        ((uint4*)(dst + ppx * PSTR))[u] = z;
    }
    {
        int px = t >> 2, cp = t & 3;
        unsigned short tmp[16];
#pragma unroll
        for (int k = 0; k < 16; ++k) tmp[k] = f2bf(tile[cp * 16 + k][px]);
        unsigned int u[8];
#pragma unroll
        for (int k = 0; k < 8; ++k) u[k] = (unsigned int)tmp[2 * k] | ((unsigned int)tmp[2 * k + 1] << 16);
        uint4 v0 = {u[0], u[1], u[2], u[3]};
        uint4 v1 = {u[4], u[5], u[6], u[7]};
        unsigned short* dp = dst + (px + 6) * PSTR + cp * 16;
        *(uint4*)dp = v0;
        *((uint4*)dp + 1) = v1;
        if (cp == 0) ((uint4*)(dst + (px + 6) * PSTR))[8] = z;
    }
}

// ---------------- K2: main conv. tile 16x16, 8 waves = 2 col-halves x 4 ks, M4N2 ----------------
// B: per-wave-private gload_lds double-buffer + REGISTER ROTATION one tap ahead.
// Iter tt consumes b0/b1v (ds_read at end of iter tt-1, latency hidden); end-of-iter
// reads tap tt+1's slot (vmcnt(2)-guaranteed landed). Slot overwrite guarded by
// lgkmcnt(0)+sched_barrier (rule #18). Zero barriers in the 169-tap loop.
// LDS ushort idx: halo [0,56448) | Bring [56448,72832) | dyn @72832 | h @73408 | P @73472.
__global__ __launch_bounds__(512, 2) void k_conv(const unsigned short* __restrict__ xpad,
                                                 const unsigned short* __restrict__ fpack,
                                                 const float* __restrict__ rs,
                                                 const float* __restrict__ w1, const float* __restrict__ b1,
                                                 const float* __restrict__ w2, const float* __restrict__ b2,
                                                 const float* __restrict__ x,
                                                 float* __restrict__ out) {
    extern __shared__ unsigned short lds[];
    unsigned short* ldsDyn = lds + 72832;            // 576 bf16
    float* ldsH = (float*)(lds + 73408);             // 32 f32
    float* ldsP = (float*)(lds + 73472);             // 64 f32
    int blk = blockIdx.x;
    int b = blk >> 4, tile = blk & 15;
    int th = tile >> 2, tw = tile & 3;
    int Y0 = th * 16, X0 = tw * 16;
    int t = threadIdx.x;
    int wave = t >> 6, l = t & 63;
    int ks = wave & 3, fc = wave >> 2;       // ks chunk, column half (cols 0-7 / 8-15)
    int l31 = l & 31, lhi = l >> 5;

    unsigned short* bring = lds + 56448 + wave * 2048;     // private 2-slot ring (2x 1024 ushort)
    const unsigned short* gB = fpack + ks * 1024 + l * 8;  // tap stride 4096 elems

    // ---- stage tap 0 into private slot 0 (drained by B1's implicit vmcnt(0)) ----
    gload16(gB, bring);
    gload16(gB + 512, bring + 512);

    // ---- wave 0: pooled fold + hidden gelu (same-wave in-order LDS; no barrier needed) ----
    if (t < 64) {
        const float* rp = rs + b * 4096 + t;
        float s = 0.f;
#pragma unroll
        for (int h = 0; h < 64; ++h) s += rp[h * 64];
        ldsP[t] = s;
        if (t < 32) {
            float s1 = b1[t];
#pragma unroll
            for (int c = 0; c < 64; ++c) s1 += ldsP[c] * w1[t * 64 + c];
            ldsH[t] = 0.5f * s1 * (1.f + erff(s1 * 0.70710678118654752f));
        }
    }

    // ---- stage halo 28 rows x 28 px (252 uint4 per row, 7056 total) ----
    {
        const unsigned short* srcb = xpad + ((size_t)(b * XPROW + Y0) * XPROW + X0) * PSTR;
        for (int k = t; k < 7056; k += 512) {
            int r = k / 252, o = k - r * 252;
            *(uint4*)(lds + r * 28 * PSTR + o * 8) =
                *(const uint4*)(srcb + (size_t)r * XPROW * PSTR + o * 8);
        }
    }
    __syncthreads();                                  // B1: halo + ldsH + tap-0 B visible

    // ---- stage2: dyn[576] -> bf16 in LDS ----
    {
        float s = b2[t];
#pragma unroll
        for (int i = 0; i < 32; ++i) s += ldsH[i] * w2[t * 32 + i];
        ldsDyn[t] = f2bf(s);
        if (t < 64) {
            int o2 = 512 + t;
            float s2 = b2[o2];
#pragma unroll
            for (int i = 0; i < 32; ++i) s2 += ldsH[i] * w2[o2 * 32 + i];
            ldsDyn[o2] = f2bf(s2);
        }
    }
    __syncthreads();                                  // B2: ldsDyn visible

    int abase = ((l31 >> 3) * 28 + fc * 8 + (l31 & 7)) * PSTR + lhi * 8 + ks * 16;

    f32x16 acc[4][2];
#pragma unroll
    for (int m = 0; m < 4; ++m)
#pragma unroll
        for (int n = 0; n < 2; ++n)
#pragma unroll
            for (int r = 0; r < 16; ++r) acc[m][n][r] = 0.f;

    // ---- prologue: stage tap 1 -> slot 1; read tap 0's B into regs ----
    gload16(gB + 4096, bring + 1024);
    gload16(gB + 4096 + 512, bring + 1024 + 512);
    short8 b0  = *(const short8*)(bring + l * 8);
    short8 b1v = *(const short8*)(bring + 512 + l * 8);

    // ---- main loop: 169 taps, register-rotated B, counted vmcnt, NO barriers ----
    int ar = abase, jj = 0;
#pragma unroll 1
    for (int tt = 0; tt < 169; ++tt) {
        // guard: b0/b1v ds_reads (into regs) completed before overwriting their slot
        asm volatile("s_waitcnt lgkmcnt(0)" ::: "memory");
        __builtin_amdgcn_sched_barrier(0);
        if (tt < 167) {
            const unsigned short* src = gB + (size_t)(tt + 2) * 4096;
            unsigned short* dstp = bring + (tt & 1) * 1024;   // current tap's slot (regs hold it)
            gload16(src, dstp);
            gload16(src + 512, dstp + 512);
        }
        asm volatile("s_waitcnt vmcnt(2)" ::: "memory");      // tap tt+1's DMA landed
        __builtin_amdgcn_s_setprio(1);
#pragma unroll
        for (int fr = 0; fr < 4; ++fr) {
            short8 a = *(const short8*)(lds + ar + fr * 8064);
            acc[fr][0] = __builtin_amdgcn_mfma_f32_32x32x16_bf16(a, b0, acc[fr][0], 0, 0, 0);
            acc[fr][1] = __builtin_amdgcn_mfma_f32_32x32x16_bf16(a, b1v, acc[fr][1], 0, 0, 0);
        }
        __builtin_amdgcn_s_setprio(0);
        if (tt < 168) {                                        // fetch next tap's B into regs
            if (tt == 167) asm volatile("s_waitcnt vmcnt(0)" ::: "memory");
            const unsigned short* bp = bring + ((tt + 1) & 1) * 1024 + l * 8;
            b0  = *(const short8*)(bp);
            b1v = *(const short8*)(bp + 512);
        }
        ++jj; ar += PSTR;
        if (jj == 13) { jj = 0; ar += 15 * PSTR; }
    }

    // ---- dynamic 3x3: diagonal B-frags from LDS dyn (bf16) ----
    {
        int ebase = ks * 16 + lhi * 8;
        int e0 = l31 - ebase;
        int e1 = 32 + l31 - ebase;
#pragma unroll
        for (int di = 0; di < 3; ++di)
#pragma unroll
            for (int dj = 0; dj < 3; ++dj) {
                int tp = di * 3 + dj;
                unsigned short v0 = ldsDyn[l31 * 9 + tp];
                unsigned short v1 = ldsDyn[(32 + l31) * 9 + tp];
                short8 d0, d1;
#pragma unroll
                for (int s = 0; s < 8; ++s) {
                    d0[s] = (s == e0) ? (short)v0 : (short)0;
                    d1[s] = (s == e1) ? (short)v1 : (short)0;
                }
                int aoff = abase + ((di + 5) * 28 + (dj + 5)) * PSTR;
#pragma unroll
                for (int fr = 0; fr < 4; ++fr) {
                    short8 a = *(const short8*)(lds + aoff + fr * 8064);
                    acc[fr][0] = __builtin_amdgcn_mfma_f32_32x32x16_bf16(a, d0, acc[fr][0], 0, 0, 0);
                    acc[fr][1] = __builtin_amdgcn_mfma_f32_32x32x16_bf16(a, d1, acc[fr][1], 0, 0, 0);
                }
            }
    }
    __syncthreads();                                  // B3: done reading halo/dyn

    // ---- cross-wave reduction over ks: lf[ks][oc(64)][px(64) pitch 65], 4 fr-rounds ----
    float* lf = (float*)lds;
#pragma unroll
    for (int fr = 0; fr < 4; ++fr) {
#pragma unroll
        for (int n = 0; n < 2; ++n)
#pragma unroll
            for (int r = 0; r < 16; ++r) {
                int oc = n * 32 + l31;
                int px = (r >> 2) * 16 + fc * 8 + (r & 3) + 4 * lhi;
                lf[ks * 4160 + oc * 65 + px] = acc[fr][n][r];
            }
        __syncthreads();
#pragma unroll
        for (int k2 = 0; k2 < 8; ++k2) {
            int e = k2 * 512 + t;          // 0..4095: oc(64) x px(64)
            int oc = e >> 6, px = e & 63;
            int idx = oc * 65 + px;
            float s = lf[idx] + lf[4160 + idx] + lf[8320 + idx] + lf[12480 + idx];
            int y = Y0 + fr * 4 + (px >> 4);
            int xx = X0 + (px & 15);
            out[((size_t)(b * XC + oc) * XH + y) * XW + xx] = s;
        }
        __syncthreads();
    }

    // ---- fused copy of x[:, 64:128] -> out ----
    {
        const uint4* xs = (const uint4*)x;
        uint4* od = (uint4*)out;
#pragma unroll
        for (int q = 0; q < 8; ++q) {
            int m4 = blk * 4096 + q * 512 + t;      // 0 .. 1,048,575
            int bi = m4 >> 16;
            int rem = m4 & 65535;
            size_t off = (size_t)bi * 131072 + 65536 + rem;
            od[off] = xs[off];
        }
    }
}

extern "C" void kernel_launch(void* const* d_in, const int* in_sizes, int n_in,
                              void* d_out, int out_size, void* d_ws, size_t ws_size,
                              hipStream_t stream) {
    const float* x  = (const float*)d_in[0];
    const float* lk = (const float*)d_in[1];
    const float* w1 = (const float*)d_in[2];
    const float* b1 = (const float*)d_in[3];
    const float* w2 = (const float*)d_in[4];
    const float* b2 = (const float*)d_in[5];
    float* out = (float*)d_out;

    char* ws = (char*)d_ws;
    float*          rs     = (float*)ws;                       //    1,048,576 B @ 0
    unsigned short* fpack  = (unsigned short*)(ws + 1048576);  //    1,384,448 B @ 1,048,576
    unsigned short* xpad   = (unsigned short*)(ws + 2605056);  //   13,307,904 B @ 2,605,056

    k_prep<<<1554, 256, 0, stream>>>(x, xpad, rs, lk, fpack);
    k_conv<<<256, 512, 147200, stream>>>(xpad, fpack, rs, w1, b1, w2, b2, x, out);
}

// Round 25
// 103.392 us; speedup vs baseline: 1.0229x; 1.0229x over previous
//
#include <hip/hip_runtime.h>
#include <hip/hip_bf16.h>

typedef short  short8  __attribute__((ext_vector_type(8)));
typedef float  f32x16  __attribute__((ext_vector_type(16)));

#define XB 16
#define XC 128
#define XH 64
#define XW 64
#define XHW 4096
#define PSTR 72            // padded elems per pixel (64 data + 8 pad), 144 B
#define XPROW 76           // padded image width/height

__device__ __forceinline__ unsigned short f2bf(float f) {
    union { float f; unsigned int u; } v; v.f = f;
    unsigned int r = (v.u + 0x7fffu + ((v.u >> 16) & 1u)) >> 16;
    return (unsigned short)r;
}

__device__ __forceinline__ void gload16(const unsigned short* g, unsigned short* s) {
    __builtin_amdgcn_global_load_lds(
        (const __attribute__((address_space(1))) void*)g,
        (__attribute__((address_space(3))) void*)s, 16, 0, 0);
}

// ---------------- K1: fused pad+convert+rowmeans (blocks 0..1215) + filter pack (1216..1553) ----------------
__global__ void k_prep(const float* __restrict__ x, unsigned short* __restrict__ xpad,
                       float* __restrict__ rs,
                       const float* __restrict__ lk, unsigned short* __restrict__ fpack) {
    int blk = blockIdx.x;
    int t = threadIdx.x;
    if (blk >= 1216) {
        int tidx = (blk - 1216) * 256 + t;       // < 86,528 exactly
        int l   = tidx & 63;
        int g   = (tidx >> 6) & 1;
        int ks  = (tidx >> 7) & 3;
        int tap = tidx >> 9;
        int oc  = g * 32 + (l & 31);
        int ic0 = ks * 16 + (l >> 5) * 8;
        unsigned short tmp[8];
#pragma unroll
        for (int e = 0; e < 8; ++e)
            tmp[e] = f2bf(lk[(size_t)(oc * 64 + ic0 + e) * 169 + tap]);
        unsigned int u[4];
#pragma unroll
        for (int k = 0; k < 4; ++k) u[k] = (unsigned int)tmp[2 * k] | ((unsigned int)tmp[2 * k + 1] << 16);
        uint4 v = {u[0], u[1], u[2], u[3]};
        *(uint4*)(fpack + (size_t)tidx * 8) = v;
        return;
    }
    int b = blk / 76, hp = blk - b * 76;
    unsigned short* dst = xpad + (size_t)(b * XPROW + hp) * XPROW * PSTR;
    uint4 z = {0u, 0u, 0u, 0u};
    if (hp < 6 || hp >= 70) {           // full zero row: 76*72 elems = 684 uint4
        for (int k = t; k < 684; k += 256) ((uint4*)dst)[k] = z;
        return;
    }
    int h = hp - 6;
    __shared__ float tile[64][65];
    __shared__ float ps[4][64];
    {
        int w = t & 63, cg = t >> 6;
#pragma unroll
        for (int k = 0; k < 16; ++k) {
            int c = cg * 16 + k;
            tile[c][w] = x[(size_t)b * XC * XHW + (size_t)c * XHW + h * 64 + w];
        }
    }
    __syncthreads();
    {
        int c = t & 63, q = t >> 6;
        float s = 0.f;
#pragma unroll
        for (int k = 0; k < 16; ++k) s += tile[c][q * 16 + k];
        ps[q][c] = s;
    }
    __syncthreads();
    if (t < 64) {
        float tot = ps[0][t] + ps[1][t] + ps[2][t] + ps[3][t];
        rs[b * 4096 + h * 64 + t] = tot * (1.f / 4096.f);
    }
    if (t < 108) {
        int px = t / 9, u = t - (t / 9) * 9;
        int ppx = px < 6 ? px : px + 64;
        ((uint4*)(dst + ppx * PSTR))[u] = z;
    }
    {
        int px = t >> 2, cp = t & 3;
        unsigned short tmp[16];
#pragma unroll
        for (int k = 0; k < 16; ++k) tmp[k] = f2bf(tile[cp * 16 + k][px]);
        unsigned int u[8];
#pragma unroll
        for (int k = 0; k < 8; ++k) u[k] = (unsigned int)tmp[2 * k] | ((unsigned int)tmp[2 * k + 1] << 16);
        uint4 v0 = {u[0], u[1], u[2], u[3]};
        uint4 v1 = {u[4], u[5], u[6], u[7]};
        unsigned short* dp = dst + (px + 6) * PSTR + cp * 16;
        *(uint4*)dp = v0;
        *((uint4*)dp + 1) = v1;
        if (cp == 0) ((uint4*)(dst + (px + 6) * PSTR))[8] = z;
    }
}

// ---------------- K2: main conv. tile 16x16, 8 waves = 2 col-halves x 4 ks, M4N2 ----------------
// B via per-wave-PRIVATE global_load_lds double-buffer, counted vmcnt(2) (never 0 in loop),
// zero barriers in the 169-tap loop. Each wave stages & reads only its own 2KB/tap -> race-free.
// Staging: lane l's 16B land at bring + l*16 bytes; read back at bring + l*8 ushorts.
// LDS ushort idx: halo [0,56448) | Bring [56448,72832) (8 waves x 2 slots x 1024) |
//                 dyn [72832,73408) | h f32 @73408 | P f32 @73472. Total 147,200 B.
__global__ __launch_bounds__(512, 2) void k_conv(const unsigned short* __restrict__ xpad,
                                                 const unsigned short* __restrict__ fpack,
                                                 const float* __restrict__ rs,
                                                 const float* __restrict__ w1, const float* __restrict__ b1,
                                                 const float* __restrict__ w2, const float* __restrict__ b2,
                                                 const float* __restrict__ x,
                                                 float* __restrict__ out) {
    extern __shared__ unsigned short lds[];
    unsigned short* ldsDyn = lds + 72832;            // 576 bf16
    float* ldsH = (float*)(lds + 73408);             // 32 f32
    float* ldsP = (float*)(lds + 73472);             // 64 f32
    int blk = blockIdx.x;
    int b = blk >> 4, tile = blk & 15;
    int th = tile >> 2, tw = tile & 3;
    int Y0 = th * 16, X0 = tw * 16;
    int t = threadIdx.x;
    int wave = t >> 6, l = t & 63;
    int ks = wave & 3, fc = wave >> 2;       // ks chunk, column half (cols 0-7 / 8-15)
    int l31 = l & 31, lhi = l >> 5;

    unsigned short* bring = lds + 56448 + wave * 2048;     // private 2-slot ring (2x 1024 ushort)
    const unsigned short* gB = fpack + ks * 1024 + l * 8;  // tap stride 4096 elems

    // ---- stage tap 0 into private slot 0 (drained by B1's implicit vmcnt(0)) ----
    gload16(gB, bring);
    gload16(gB + 512, bring + 512);

    // ---- wave 0: pooled fold + hidden gelu (same-wave in-order LDS; no barrier needed) ----
    if (t < 64) {
        const float* rp = rs + b * 4096 + t;
        float s = 0.f;
#pragma unroll
        for (int h = 0; h < 64; ++h) s += rp[h * 64];
        ldsP[t] = s;
        if (t < 32) {
            float s1 = b1[t];
#pragma unroll
            for (int c = 0; c < 64; ++c) s1 += ldsP[c] * w1[t * 64 + c];
            ldsH[t] = 0.5f * s1 * (1.f + erff(s1 * 0.70710678118654752f));
        }
    }

    // ---- stage halo 28 rows x 28 px (252 uint4 per row, 7056 total) ----
    {
        const unsigned short* srcb = xpad + ((size_t)(b * XPROW + Y0) * XPROW + X0) * PSTR;
        for (int k = t; k < 7056; k += 512) {
            int r = k / 252, o = k - r * 252;
            *(uint4*)(lds + r * 28 * PSTR + o * 8) =
                *(const uint4*)(srcb + (size_t)r * XPROW * PSTR + o * 8);
        }
    }
    __syncthreads();                                  // B1: halo + ldsH (+ tap-0 B) visible

    // ---- stage2: dyn[576] -> bf16 in LDS ----
    {
        float s = b2[t];
#pragma unroll
        for (int i = 0; i < 32; ++i) s += ldsH[i] * w2[t * 32 + i];
        ldsDyn[t] = f2bf(s);
        if (t < 64) {
            int o2 = 512 + t;
            float s2 = b2[o2];
#pragma unroll
            for (int i = 0; i < 32; ++i) s2 += ldsH[i] * w2[o2 * 32 + i];
            ldsDyn[o2] = f2bf(s2);
        }
    }
    __syncthreads();                                  // B2: ldsDyn visible

    int abase = ((l31 >> 3) * 28 + fc * 8 + (l31 & 7)) * PSTR + lhi * 8 + ks * 16;

    f32x16 acc[4][2];
#pragma unroll
    for (int m = 0; m < 4; ++m)
#pragma unroll
        for (int n = 0; n < 2; ++n)
#pragma unroll
            for (int r = 0; r < 16; ++r) acc[m][n][r] = 0.f;

    // ---- main loop: 169 taps, private B-ring, counted vmcnt, NO barriers ----
    int ar = abase, jj = 0;
#pragma unroll 1
    for (int tt = 0; tt < 169; ++tt) {
        if (tt < 168) {
            const unsigned short* src = gB + (size_t)(tt + 1) * 4096;
            unsigned short* dstp = bring + ((tt + 1) & 1) * 1024;
            gload16(src, dstp);
            gload16(src + 512, dstp + 512);
            asm volatile("s_waitcnt vmcnt(2)" ::: "memory");   // tap tt's 2 loads retired
        } else {
            asm volatile("s_waitcnt vmcnt(0)" ::: "memory");
        }
        const unsigned short* bp = bring + (tt & 1) * 1024 + l * 8;   // +l*8: own fragment
        short8 b0  = *(const short8*)(bp);
        short8 b1v = *(const short8*)(bp + 512);
        __builtin_amdgcn_s_setprio(1);
#pragma unroll
        for (int fr = 0; fr < 4; ++fr) {
            short8 a = *(const short8*)(lds + ar + fr * 8064);
            acc[fr][0] = __builtin_amdgcn_mfma_f32_32x32x16_bf16(a, b0, acc[fr][0], 0, 0, 0);
            acc[fr][1] = __builtin_amdgcn_mfma_f32_32x32x16_bf16(a, b1v, acc[fr][1], 0, 0, 0);
        }
        __builtin_amdgcn_s_setprio(0);
        ++jj; ar += PSTR;
        if (jj == 13) { jj = 0; ar += 15 * PSTR; }
    }

    // ---- dynamic 3x3: diagonal B-frags from LDS dyn (bf16) ----
    {
        int ebase = ks * 16 + lhi * 8;
        int e0 = l31 - ebase;
        int e1 = 32 + l31 - ebase;
#pragma unroll
        for (int di = 0; di < 3; ++di)
#pragma unroll
            for (int dj = 0; dj < 3; ++dj) {
                int tp = di * 3 + dj;
                unsigned short v0 = ldsDyn[l31 * 9 + tp];
                unsigned short v1 = ldsDyn[(32 + l31) * 9 + tp];
                short8 b0, b1v;
#pragma unroll
                for (int s = 0; s < 8; ++s) {
                    b0[s] = (s == e0) ? (short)v0 : (short)0;
                    b1v[s] = (s == e1) ? (short)v1 : (short)0;
                }
                int aoff = abase + ((di + 5) * 28 + (dj + 5)) * PSTR;
#pragma unroll
                for (int fr = 0; fr < 4; ++fr) {
                    short8 a = *(const short8*)(lds + aoff + fr * 8064);
                    acc[fr][0] = __builtin_amdgcn_mfma_f32_32x32x16_bf16(a, b0, acc[fr][0], 0, 0, 0);
                    acc[fr][1] = __builtin_amdgcn_mfma_f32_32x32x16_bf16(a, b1v, acc[fr][1], 0, 0, 0);
                }
            }
    }
    __syncthreads();                                  // B3: done reading halo/dyn

    // ---- cross-wave reduction over ks: lf[ks][oc(64)][px(64) pitch 65], 4 fr-rounds ----
    float* lf = (float*)lds;
#pragma unroll
    for (int fr = 0; fr < 4; ++fr) {
#pragma unroll
        for (int n = 0; n < 2; ++n)
#pragma unroll
            for (int r = 0; r < 16; ++r) {
                int oc = n * 32 + l31;
                int px = (r >> 2) * 16 + fc * 8 + (r & 3) + 4 * lhi;
                lf[ks * 4160 + oc * 65 + px] = acc[fr][n][r];
            }
        __syncthreads();
#pragma unroll
        for (int k2 = 0; k2 < 8; ++k2) {
            int e = k2 * 512 + t;          // 0..4095: oc(64) x px(64)
            int oc = e >> 6, px = e & 63;
            int idx = oc * 65 + px;
            float s = lf[idx] + lf[4160 + idx] + lf[8320 + idx] + lf[12480 + idx];
            int y = Y0 + fr * 4 + (px >> 4);
            int xx = X0 + (px & 15);
            out[((size_t)(b * XC + oc) * XH + y) * XW + xx] = s;
        }
        __syncthreads();
    }

    // ---- fused copy of x[:, 64:128] -> out ----
    {
        const uint4* xs = (const uint4*)x;
        uint4* od = (uint4*)out;
#pragma unroll
        for (int q = 0; q < 8; ++q) {
            int m4 = blk * 4096 + q * 512 + t;      // 0 .. 1,048,575
            int bi = m4 >> 16;
            int rem = m4 & 65535;
            size_t off = (size_t)bi * 131072 + 65536 + rem;
            od[off] = xs[off];
        }
    }
}

extern "C" void kernel_launch(void* const* d_in, const int* in_sizes, int n_in,
                              void* d_out, int out_size, void* d_ws, size_t ws_size,
                              hipStream_t stream) {
    const float* x  = (const float*)d_in[0];
    const float* lk = (const float*)d_in[1];
    const float* w1 = (const float*)d_in[2];
    const float* b1 = (const float*)d_in[3];
    const float* w2 = (const float*)d_in[4];
    const float* b2 = (const float*)d_in[5];
    float* out = (float*)d_out;

    char* ws = (char*)d_ws;
    float*          rs     = (float*)ws;                       //    1,048,576 B @ 0
    unsigned short* fpack  = (unsigned short*)(ws + 1048576);  //    1,384,448 B @ 1,048,576
    unsigned short* xpad   = (unsigned short*)(ws + 2605056);  //   13,307,904 B @ 2,605,056

    k_prep<<<1554, 256, 0, stream>>>(x, xpad, rs, lk, fpack);
    k_conv<<<256, 512, 147200, stream>>>(xpad, fpack, rs, w1, b1, w2, b2, x, out);
}

// Round 26
// 103.096 us; speedup vs baseline: 1.0258x; 1.0029x over previous
//
#include <hip/hip_runtime.h>
#include <hip/hip_bf16.h>

typedef short  short8  __attribute__((ext_vector_type(8)));
typedef float  f32x16  __attribute__((ext_vector_type(16)));

#define XB 16
#define XC 128
#define XH 64
#define XW 64
#define XHW 4096
#define PSTR 72            // padded elems per pixel (64 data + 8 pad), 144 B
#define XPROW 76           // padded image width/height

__device__ __forceinline__ unsigned short f2bf(float f) {
    union { float f; unsigned int u; } v; v.f = f;
    unsigned int r = (v.u + 0x7fffu + ((v.u >> 16) & 1u)) >> 16;
    return (unsigned short)r;
}

__device__ __forceinline__ void gload16(const unsigned short* g, unsigned short* s) {
    __builtin_amdgcn_global_load_lds(
        (const __attribute__((address_space(1))) void*)g,
        (__attribute__((address_space(3))) void*)s, 16, 0, 0);
}

// ---------------- K1: fused pad+convert+rowmeans (blocks 0..1215) + filter pack (1216..1553) ----------------
__global__ void k_prep(const float* __restrict__ x, unsigned short* __restrict__ xpad,
                       float* __restrict__ rs,
                       const float* __restrict__ lk, unsigned short* __restrict__ fpack) {
    int blk = blockIdx.x;
    int t = threadIdx.x;
    if (blk >= 1216) {
        int tidx = (blk - 1216) * 256 + t;       // < 86,528 exactly
        int l   = tidx & 63;
        int g   = (tidx >> 6) & 1;
        int ks  = (tidx >> 7) & 3;
        int tap = tidx >> 9;
        int oc  = g * 32 + (l & 31);
        int ic0 = ks * 16 + (l >> 5) * 8;
        unsigned short tmp[8];
#pragma unroll
        for (int e = 0; e < 8; ++e)
            tmp[e] = f2bf(lk[(size_t)(oc * 64 + ic0 + e) * 169 + tap]);
        unsigned int u[4];
#pragma unroll
        for (int k = 0; k < 4; ++k) u[k] = (unsigned int)tmp[2 * k] | ((unsigned int)tmp[2 * k + 1] << 16);
        uint4 v = {u[0], u[1], u[2], u[3]};
        *(uint4*)(fpack + (size_t)tidx * 8) = v;
        return;
    }
    int b = blk / 76, hp = blk - b * 76;
    unsigned short* dst = xpad + (size_t)(b * XPROW + hp) * XPROW * PSTR;
    uint4 z = {0u, 0u, 0u, 0u};
    if (hp < 6 || hp >= 70) {           // full zero row: 76*72 elems = 684 uint4
        for (int k = t; k < 684; k += 256) ((uint4*)dst)[k] = z;
        return;
    }
    int h = hp - 6;
    __shared__ float tile[64][65];
    __shared__ float ps[4][64];
    {
        int w = t & 63, cg = t >> 6;
#pragma unroll
        for (int k = 0; k < 16; ++k) {
            int c = cg * 16 + k;
            tile[c][w] = x[(size_t)b * XC * XHW + (size_t)c * XHW + h * 64 + w];
        }
    }
    __syncthreads();
    {
        int c = t & 63, q = t >> 6;
        float s = 0.f;
#pragma unroll
        for (int k = 0; k < 16; ++k) s += tile[c][q * 16 + k];
        ps[q][c] = s;
    }
    __syncthreads();
    if (t < 64) {
        float tot = ps[0][t] + ps[1][t] + ps[2][t] + ps[3][t];
        rs[b * 4096 + h * 64 + t] = tot * (1.f / 4096.f);
    }
    if (t < 108) {
        int px = t / 9, u = t - (t / 9) * 9;
        int ppx = px < 6 ? px : px + 64;
        ((uint4*)(dst + ppx * PSTR))[u] = z;
    }
    {
        int px = t >> 2, cp = t & 3;
        unsigned short tmp[16];
#pragma unroll
        for (int k = 0; k < 16; ++k) tmp[k] = f2bf(tile[cp * 16 + k][px]);
        unsigned int u[8];
#pragma unroll
        for (int k = 0; k < 8; ++k) u[k] = (unsigned int)tmp[2 * k] | ((unsigned int)tmp[2 * k + 1] << 16);
        uint4 v0 = {u[0], u[1], u[2], u[3]};
        uint4 v1 = {u[4], u[5], u[6], u[7]};
        unsigned short* dp = dst + (px + 6) * PSTR + cp * 16;
        *(uint4*)dp = v0;
        *((uint4*)dp + 1) = v1;
        if (cp == 0) ((uint4*)(dst + (px + 6) * PSTR))[8] = z;
    }
}

// ---------------- K2: main conv. tile 16x16, 8 waves = 2 col-halves x 4 ks, M4N2 ----------------
// B via per-wave-PRIVATE global_load_lds double-buffer, counted vmcnt(2), zero barriers in loop.
// Epilogue: TWO fr-planes per round (133,120 B <= 147,200 B LDS) -> 2 rounds instead of 4.
// LDS ushort idx: halo [0,56448) | Bring [56448,72832) | dyn @72832 | h @73408 | P @73472.
__global__ __launch_bounds__(512, 2) void k_conv(const unsigned short* __restrict__ xpad,
                                                 const unsigned short* __restrict__ fpack,
                                                 const float* __restrict__ rs,
                                                 const float* __restrict__ w1, const float* __restrict__ b1,
                                                 const float* __restrict__ w2, const float* __restrict__ b2,
                                                 const float* __restrict__ x,
                                                 float* __restrict__ out) {
    extern __shared__ unsigned short lds[];
    unsigned short* ldsDyn = lds + 72832;            // 576 bf16
    float* ldsH = (float*)(lds + 73408);             // 32 f32
    float* ldsP = (float*)(lds + 73472);             // 64 f32
    int blk = blockIdx.x;
    int b = blk >> 4, tile = blk & 15;
    int th = tile >> 2, tw = tile & 3;
    int Y0 = th * 16, X0 = tw * 16;
    int t = threadIdx.x;
    int wave = t >> 6, l = t & 63;
    int ks = wave & 3, fc = wave >> 2;       // ks chunk, column half (cols 0-7 / 8-15)
    int l31 = l & 31, lhi = l >> 5;

    unsigned short* bring = lds + 56448 + wave * 2048;     // private 2-slot ring (2x 1024 ushort)
    const unsigned short* gB = fpack + ks * 1024 + l * 8;  // tap stride 4096 elems

    // ---- stage tap 0 into private slot 0 (drained by B1's implicit vmcnt(0)) ----
    gload16(gB, bring);
    gload16(gB + 512, bring + 512);

    // ---- wave 0: pooled fold + hidden gelu (same-wave in-order LDS; no barrier needed) ----
    if (t < 64) {
        const float* rp = rs + b * 4096 + t;
        float s = 0.f;
#pragma unroll
        for (int h = 0; h < 64; ++h) s += rp[h * 64];
        ldsP[t] = s;
        if (t < 32) {
            float s1 = b1[t];
#pragma unroll
            for (int c = 0; c < 64; ++c) s1 += ldsP[c] * w1[t * 64 + c];
            ldsH[t] = 0.5f * s1 * (1.f + erff(s1 * 0.70710678118654752f));
        }
    }

    // ---- stage halo 28 rows x 28 px (252 uint4 per row, 7056 total) ----
    {
        const unsigned short* srcb = xpad + ((size_t)(b * XPROW + Y0) * XPROW + X0) * PSTR;
        for (int k = t; k < 7056; k += 512) {
            int r = k / 252, o = k - r * 252;
            *(uint4*)(lds + r * 28 * PSTR + o * 8) =
                *(const uint4*)(srcb + (size_t)r * XPROW * PSTR + o * 8);
        }
    }
    __syncthreads();                                  // B1: halo + ldsH (+ tap-0 B) visible

    // ---- stage2: dyn[576] -> bf16 in LDS ----
    {
        float s = b2[t];
#pragma unroll
        for (int i = 0; i < 32; ++i) s += ldsH[i] * w2[t * 32 + i];
        ldsDyn[t] = f2bf(s);
        if (t < 64) {
            int o2 = 512 + t;
            float s2 = b2[o2];
#pragma unroll
            for (int i = 0; i < 32; ++i) s2 += ldsH[i] * w2[o2 * 32 + i];
            ldsDyn[o2] = f2bf(s2);
        }
    }
    __syncthreads();                                  // B2: ldsDyn visible

    int abase = ((l31 >> 3) * 28 + fc * 8 + (l31 & 7)) * PSTR + lhi * 8 + ks * 16;

    f32x16 acc[4][2];
#pragma unroll
    for (int m = 0; m < 4; ++m)
#pragma unroll
        for (int n = 0; n < 2; ++n)
#pragma unroll
            for (int r = 0; r < 16; ++r) acc[m][n][r] = 0.f;

    // ---- main loop: 169 taps, private B-ring, counted vmcnt, NO barriers ----
    int ar = abase, jj = 0;
#pragma unroll 1
    for (int tt = 0; tt < 169; ++tt) {
        if (tt < 168) {
            const unsigned short* src = gB + (size_t)(tt + 1) * 4096;
            unsigned short* dstp = bring + ((tt + 1) & 1) * 1024;
            gload16(src, dstp);
            gload16(src + 512, dstp + 512);
            asm volatile("s_waitcnt vmcnt(2)" ::: "memory");   // tap tt's 2 loads retired
        } else {
            asm volatile("s_waitcnt vmcnt(0)" ::: "memory");
        }
        const unsigned short* bp = bring + (tt & 1) * 1024 + l * 8;   // +l*8: own fragment
        short8 b0  = *(const short8*)(bp);
        short8 b1v = *(const short8*)(bp + 512);
        __builtin_amdgcn_s_setprio(1);
#pragma unroll
        for (int fr = 0; fr < 4; ++fr) {
            short8 a = *(const short8*)(lds + ar + fr * 8064);
            acc[fr][0] = __builtin_amdgcn_mfma_f32_32x32x16_bf16(a, b0, acc[fr][0], 0, 0, 0);
            acc[fr][1] = __builtin_amdgcn_mfma_f32_32x32x16_bf16(a, b1v, acc[fr][1], 0, 0, 0);
        }
        __builtin_amdgcn_s_setprio(0);
        ++jj; ar += PSTR;
        if (jj == 13) { jj = 0; ar += 15 * PSTR; }
    }

    // ---- dynamic 3x3: diagonal B-frags from LDS dyn (bf16) ----
    {
        int ebase = ks * 16 + lhi * 8;
        int e0 = l31 - ebase;
        int e1 = 32 + l31 - ebase;
#pragma unroll
        for (int di = 0; di < 3; ++di)
#pragma unroll
            for (int dj = 0; dj < 3; ++dj) {
                int tp = di * 3 + dj;
                unsigned short v0 = ldsDyn[l31 * 9 + tp];
                unsigned short v1 = ldsDyn[(32 + l31) * 9 + tp];
                short8 b0, b1v;
#pragma unroll
                for (int s = 0; s < 8; ++s) {
                    b0[s] = (s == e0) ? (short)v0 : (short)0;
                    b1v[s] = (s == e1) ? (short)v1 : (short)0;
                }
                int aoff = abase + ((di + 5) * 28 + (dj + 5)) * PSTR;
#pragma unroll
                for (int fr = 0; fr < 4; ++fr) {
                    short8 a = *(const short8*)(lds + aoff + fr * 8064);
                    acc[fr][0] = __builtin_amdgcn_mfma_f32_32x32x16_bf16(a, b0, acc[fr][0], 0, 0, 0);
                    acc[fr][1] = __builtin_amdgcn_mfma_f32_32x32x16_bf16(a, b1v, acc[fr][1], 0, 0, 0);
                }
            }
    }
    __syncthreads();                                  // B3: done reading halo/dyn

    // ---- cross-wave reduction over ks: TWO fr-planes per round, 2 rounds ----
    // lf[ff][ks][oc(64)][px(64) pitch 65]: ff stride 16,640 f32; total 133,120 B.
    float* lf = (float*)lds;
#pragma unroll
    for (int fr2 = 0; fr2 < 2; ++fr2) {
#pragma unroll
        for (int ff = 0; ff < 2; ++ff)
#pragma unroll
            for (int n = 0; n < 2; ++n)
#pragma unroll
                for (int r = 0; r < 16; ++r) {
                    int oc = n * 32 + l31;
                    int px = (r >> 2) * 16 + fc * 8 + (r & 3) + 4 * lhi;
                    lf[ff * 16640 + ks * 4160 + oc * 65 + px] = acc[fr2 * 2 + ff][n][r];
                }
        __syncthreads();
#pragma unroll
        for (int k2 = 0; k2 < 16; ++k2) {
            int e = k2 * 512 + t;          // 0..8191: ff(2) x oc(64) x px(64)
            int ff = e >> 12, e2 = e & 4095;
            int oc = e2 >> 6, px = e2 & 63;
            int idx = ff * 16640 + oc * 65 + px;
            float s = lf[idx] + lf[4160 + idx] + lf[8320 + idx] + lf[12480 + idx];
            int y = Y0 + (fr2 * 2 + ff) * 4 + (px >> 4);
            int xx = X0 + (px & 15);
            out[((size_t)(b * XC + oc) * XH + y) * XW + xx] = s;
        }
        __syncthreads();
    }

    // ---- fused copy of x[:, 64:128] -> out ----
    {
        const uint4* xs = (const uint4*)x;
        uint4* od = (uint4*)out;
#pragma unroll
        for (int q = 0; q < 8; ++q) {
            int m4 = blk * 4096 + q * 512 + t;      // 0 .. 1,048,575
            int bi = m4 >> 16;
            int rem = m4 & 65535;
            size_t off = (size_t)bi * 131072 + 65536 + rem;
            od[off] = xs[off];
        }
    }
}

extern "C" void kernel_launch(void* const* d_in, const int* in_sizes, int n_in,
                              void* d_out, int out_size, void* d_ws, size_t ws_size,
                              hipStream_t stream) {
    const float* x  = (const float*)d_in[0];
    const float* lk = (const float*)d_in[1];
    const float* w1 = (const float*)d_in[2];
    const float* b1 = (const float*)d_in[3];
    const float* w2 = (const float*)d_in[4];
    const float* b2 = (const float*)d_in[5];
    float* out = (float*)d_out;

    char* ws = (char*)d_ws;
    float*          rs     = (float*)ws;                       //    1,048,576 B @ 0
    unsigned short* fpack  = (unsigned short*)(ws + 1048576);  //    1,384,448 B @ 1,048,576
    unsigned short* xpad   = (unsigned short*)(ws + 2605056);  //   13,307,904 B @ 2,605,056

    k_prep<<<1554, 256, 0, stream>>>(x, xpad, rs, lk, fpack);
    k_conv<<<256, 512, 147200, stream>>>(xpad, fpack, rs, w1, b1, w2, b2, x, out);
}